// Round 7
// baseline (857.374 us; speedup 1.0000x reference)
//
#include <hip/hip_runtime.h>
#include <hip/hip_bf16.h>

#define Bdim 32
#define Ndim 4096
#define Cdim 768
#define Kdim 64

typedef float f32x4 __attribute__((ext_vector_type(4)));
typedef short s16x8 __attribute__((ext_vector_type(8)));
typedef __bf16 bf16x8 __attribute__((ext_vector_type(8)));

__device__ __forceinline__ short f2bf(float f) {
  return __builtin_bit_cast(short, (__bf16)f);   // hw RNE cvt
}
__device__ __forceinline__ float bf2f(short s) {
  return (float)__builtin_bit_cast(__bf16, s);
}
__device__ __forceinline__ f32x4 MFMA(s16x8 a, s16x8 b, f32x4 c) {
  return __builtin_amdgcn_mfma_f32_16x16x32_bf16(
      __builtin_bit_cast(bf16x8, a), __builtin_bit_cast(bf16x8, b), c, 0, 0, 0);
}

// ---------------- k0: W fp32 -> bf16 ----------------
__global__ void k0_wcvt(const float* __restrict__ W, short* __restrict__ Wb) {
  int idx = blockIdx.x * 256 + threadIdx.x;
  if (idx < Kdim * Cdim) Wb[idx] = f2bf(W[idx]);
}

// ---------------- k1: logits = x @ W^T (exotic layout) + fused per-tile stats ----
// DIAGNOSTIC: nrep-loop repeats identical work to make this dispatch top-5
// visible in rocprof (all reps write identical values; deterministic).
__global__ __launch_bounds__(256) void k1_logits(
    const float* __restrict__ x, const short* __restrict__ Wb,
    short* __restrict__ Lx, float* __restrict__ pm, float* __restrict__ ps,
    int nrep) {
  const int blk = blockIdx.x;
  const int b = blk >> 6;          // 64 ntiles per batch
  const int ntile = blk & 63;      // 64 rows per tile
  const int tid = threadIdx.x;
  const int w = tid >> 6;          // wave id 0..3 -> rows 16w..16w+15
  const int l = tid & 63;
  const int g = l >> 4, i = l & 15;

  __shared__ float rm[4][4][16], rs[4][4][16];  // [w][t][i]

  for (int rep = 0; rep < nrep; ++rep) {
    __syncthreads();  // protect shared reuse across reps

    const float* xrow = x + (size_t)(b * Ndim + ntile * 64 + w * 16 + i) * Cdim;
    f32x4 acc[4] = {};

    for (int cs = 0; cs < Cdim / 32; ++cs) {
      const int c0 = cs * 32 + g * 8;
      const f32x4* ap = (const f32x4*)(xrow + c0);
      f32x4 a0 = ap[0];
      f32x4 a1 = ap[1];
      s16x8 af;
#pragma unroll
      for (int e = 0; e < 4; ++e) af[e] = f2bf(a0[e]);
#pragma unroll
      for (int e = 0; e < 4; ++e) af[4 + e] = f2bf(a1[e]);
#pragma unroll
      for (int t = 0; t < 4; ++t) {
        s16x8 bfr = *(const s16x8*)(Wb + (t * 16 + i) * Cdim + c0);
        acc[t] = MFMA(af, bfr, acc[t]);
      }
    }

    // store logits (rounded) + keep rounded values for stats
    short* Lb = Lx + (size_t)b * (Ndim * Kdim);
    float rnd[4][4];
#pragma unroll
    for (int t = 0; t < 4; ++t) {
#pragma unroll
      for (int r = 0; r < 4; ++r) {
        int n = ntile * 64 + w * 16 + g * 4 + r;  // D row = 4*(l>>4)+reg
        int k = t * 16 + i;                       // D col = l&15
        short hv = f2bf(acc[t][r]);
        Lb[(n >> 3) * 512 + k * 8 + (n & 7)] = hv;
        rnd[t][r] = bf2f(hv);
      }
    }

    // ---- fused per-tile (max, sum-exp) over the tile's 64 n for each k ----
    float tm[4];
#pragma unroll
    for (int t = 0; t < 4; ++t) {
      tm[t] = fmaxf(fmaxf(rnd[t][0], rnd[t][1]), fmaxf(rnd[t][2], rnd[t][3]));
      tm[t] = fmaxf(tm[t], __shfl_xor(tm[t], 16));
      tm[t] = fmaxf(tm[t], __shfl_xor(tm[t], 32));
    }
    if (g == 0) {
#pragma unroll
      for (int t = 0; t < 4; ++t) rm[w][t][i] = tm[t];
    }
    __syncthreads();
    float M[4], sv[4];
#pragma unroll
    for (int t = 0; t < 4; ++t) {
      M[t] = fmaxf(fmaxf(rm[0][t][i], rm[1][t][i]), fmaxf(rm[2][t][i], rm[3][t][i]));
      sv[t] = __expf(rnd[t][0] - M[t]) + __expf(rnd[t][1] - M[t]) +
              __expf(rnd[t][2] - M[t]) + __expf(rnd[t][3] - M[t]);
      sv[t] += __shfl_xor(sv[t], 16);
      sv[t] += __shfl_xor(sv[t], 32);
    }
    if (g == 0) {
#pragma unroll
      for (int t = 0; t < 4; ++t) rs[w][t][i] = sv[t];
    }
    __syncthreads();
    if (w == 0 && g == 0) {
#pragma unroll
      for (int t = 0; t < 4; ++t) {
        float S = rs[0][t][i] + rs[1][t][i] + rs[2][t][i] + rs[3][t][i];
        pm[((size_t)b * 64 + ntile) * 64 + t * 16 + i] = M[t];
        ps[((size_t)b * 64 + ntile) * 64 + t * 16 + i] = S;
      }
    }
  }
}

// ---------------- k2b: combine 64 tile-partials -> m, 1/denom ----------------
__global__ __launch_bounds__(256) void k2b_combine(
    const float* __restrict__ pm, const float* __restrict__ ps,
    float* __restrict__ mout, float* __restrict__ invd) {
  const int idx = blockIdx.x * 256 + threadIdx.x;  // = b*64 + k
  const int b = idx >> 6, k = idx & 63;
  float am[64];
#pragma unroll 64
  for (int nt = 0; nt < 64; ++nt) am[nt] = pm[((size_t)b * 64 + nt) * 64 + k];
  float M = am[0];
#pragma unroll 64
  for (int nt = 1; nt < 64; ++nt) M = fmaxf(M, am[nt]);
  float S = 0.f;
#pragma unroll 64
  for (int nt = 0; nt < 64; ++nt)
    S += ps[((size_t)b * 64 + nt) * 64 + k] * __expf(am[nt] - M);
  mout[idx] = M;
  invd[idx] = 1.f / S;
}

// ---------------- k3: partial_q[b,k,c] = sum_{n in quarter q} exp(s-m) * x[b,n,c] ----
// DIAGNOSTIC: nrep-loop (identical reps) for rocprof visibility.
#define CT 48    // c-columns per block
#define NCH 128  // n rows staged per chunk
#define NQ 4     // n-splits
__device__ __forceinline__ int swz(int c) {
  return ((((c >> 3) ^ c) & 7) << 4);  // byte-XOR within a 256B row
}
__global__ __launch_bounds__(256) void k3_tokens(
    const float* __restrict__ x, const short* __restrict__ Lx,
    const float* __restrict__ mv, float* __restrict__ part, int nrep) {
  __shared__ short xs[CT * 128];  // CT rows x 256 bytes
  char* xsb = (char*)xs;
  const int blk = blockIdx.x;
  const int q = blk & 3;
  const int ct = (blk >> 2) & 15;
  const int b = blk >> 6;
  const int tid = threadIdx.x;
  const int w = tid >> 6, l = tid & 63, g = l >> 4, i = l & 15;

  const float* xb = x + (size_t)b * Ndim * Cdim;
  const short* Lb = Lx + (size_t)b * (Ndim * Kdim);
  const float mk = mv[b * Kdim + w * 16 + i];  // A row k = w*16 + (l&15)

#define LOADX(ch, buf)                                                        \
  do {                                                                        \
    const int n0_ = (ch) * NCH;                                               \
    _Pragma("unroll") for (int uu = 0; uu < 3; ++uu) {                        \
      int u_ = tid + uu * 256;                                                \
      int n_ = u_ / 6, c8_ = u_ % 6;                                          \
      const f32x4* src_ =                                                     \
          (const f32x4*)(xb + (size_t)(n0_ + n_) * Cdim + ct * CT + c8_ * 8); \
      buf[uu][0] = src_[0];                                                   \
      buf[uu][1] = src_[1];                                                   \
    }                                                                         \
  } while (0)

#define LOADL(ch, lvb)                                                        \
  do {                                                                        \
    const int nb8_ = (ch) * 16;                                               \
    _Pragma("unroll") for (int ns = 0; ns < 4; ++ns) {                        \
      lvb[ns] = *(const s16x8*)(Lb + (size_t)(nb8_ + ns * 4 + g) * 512 +      \
                                (w * 16 + i) * 8);                            \
    }                                                                         \
  } while (0)

#define STORELDS(buf)                                                         \
  do {                                                                        \
    _Pragma("unroll") for (int uu = 0; uu < 3; ++uu) {                        \
      int u_ = tid + uu * 256;                                                \
      int n_ = u_ / 6, c8_ = u_ % 6;                                          \
      _Pragma("unroll") for (int e = 0; e < 8; ++e) {                         \
        int c_ = c8_ * 8 + e;                                                 \
        float fv_ = (e < 4) ? buf[uu][0][e] : buf[uu][1][e - 4];              \
        *(short*)(xsb + c_ * 256 + ((2 * n_) ^ swz(c_))) = f2bf(fv_);         \
      }                                                                       \
    }                                                                         \
  } while (0)

#define COMPUTE(lvb)                                                          \
  do {                                                                        \
    _Pragma("unroll") for (int ns = 0; ns < 4; ++ns) {                        \
      s16x8 af_;                                                              \
      _Pragma("unroll") for (int e = 0; e < 8; ++e)                           \
          af_[e] = f2bf(__expf(bf2f(lvb[ns][e]) - mk));                       \
      _Pragma("unroll") for (int cs = 0; cs < 3; ++cs) {                      \
        const int c_ = cs * 16 + i;                                           \
        s16x8 bfr_ = *(const s16x8*)(xsb + c_ * 256 +                         \
                                     ((ns * 64 + g * 16) ^ swz(c_)));         \
        acc[cs] = MFMA(af_, bfr_, acc[cs]);                                   \
      }                                                                       \
    }                                                                         \
  } while (0)

  for (int rep = 0; rep < nrep; ++rep) {
    __syncthreads();  // protect LDS reuse across reps
    f32x4 acc[3] = {};
    f32x4 stA[3][2], stB[3][2];
    s16x8 lvA[4], lvB[4];

    const int ch0 = q * 8;  // 8 chunks of 128 n per block
    LOADX(ch0, stA);
    LOADL(ch0, lvA);
    for (int ch = 0; ch < 8; ch += 2) {
      __syncthreads();
      STORELDS(stA);
      LOADX(ch0 + ch + 1, stB);
      LOADL(ch0 + ch + 1, lvB);
      __syncthreads();
      COMPUTE(lvA);
      __syncthreads();
      STORELDS(stB);
      if (ch + 2 < 8) {
        LOADX(ch0 + ch + 2, stA);
        LOADL(ch0 + ch + 2, lvA);
      }
      __syncthreads();
      COMPUTE(lvB);
    }

    float* pb = part + ((size_t)q * Bdim + b) * (Kdim * Cdim);
#pragma unroll
    for (int r = 0; r < 4; ++r) {
      const int k = w * 16 + g * 4 + r;  // D row
#pragma unroll
      for (int cs = 0; cs < 3; ++cs) {
        pb[(size_t)k * Cdim + ct * CT + cs * 16 + i] = acc[cs][r];  // D col = i
      }
    }
  }
#undef LOADX
#undef LOADL
#undef STORELDS
#undef COMPUTE
}

// ---------------- k4: out = invd * sum_q part[q] ----------------
#define QSTRIDE (Bdim * Kdim * Cdim / 4)  // f32x4 units per q-slice = 393216
__global__ __launch_bounds__(256) void k4_reduce(
    const float* __restrict__ part, const float* __restrict__ invd,
    float* __restrict__ out) {
  const int idx = blockIdx.x * 256 + threadIdx.x;  // f32x4 unit index
  const f32x4* p = (const f32x4*)part;
  f32x4 s = p[idx] + p[idx + QSTRIDE] + p[idx + 2 * QSTRIDE] + p[idx + 3 * QSTRIDE];
  const float sc = invd[(idx * 4) / Cdim];  // (b*64+k)
  ((f32x4*)out)[idx] = s * sc;
}

extern "C" void kernel_launch(void* const* d_in, const int* in_sizes, int n_in,
                              void* d_out, int out_size, void* d_ws, size_t ws_size,
                              hipStream_t stream) {
  const float* x = (const float*)d_in[0];
  const float* W = (const float*)d_in[1];
  float* out = (float*)d_out;
  char* ws = (char*)d_ws;

  short* Wb = (short*)ws;                                   // 96 KB (pad 128K)
  short* Lx = (short*)(ws + (1 << 17));                     // 16 MB bf16 logits
  char* after = ws + (1 << 17) + (size_t)Bdim * Ndim * Kdim * 2;
  float* pm = (float*)after;                                // [32][64][64] tile max
  float* psum = pm + Bdim * 64 * 64;                        // [32][64][64] tile sum
  float* mv = psum + Bdim * 64 * 64;                        // 2048 max
  float* iv = mv + Bdim * Kdim;                             // 2048 inv-denom
  float* part = iv + Bdim * Kdim;                           // [4][32][64][768] fp32

  // DIAGNOSTIC ROUND: k1/k3 repeat identical work 4x (runtime arg) so their
  // dispatches crack the rocprof top-5 and expose true per-kernel counters.
  hipLaunchKernelGGL(k0_wcvt, dim3(192), dim3(256), 0, stream, W, Wb);
  hipLaunchKernelGGL(k1_logits, dim3(Bdim * 64), dim3(256), 0, stream, x, Wb, Lx, pm, psum, 4);
  hipLaunchKernelGGL(k2b_combine, dim3(8), dim3(256), 0, stream, pm, psum, mv, iv);
  hipLaunchKernelGGL(k3_tokens, dim3(Bdim * 16 * NQ), dim3(256), 0, stream, x, Lx, mv, part, 4);
  hipLaunchKernelGGL(k4_reduce, dim3(Bdim * Kdim * Cdim / 4 / 256), dim3(256), 0, stream,
                     part, iv, out);
}

// Round 8
// 219.551 us; speedup vs baseline: 3.9051x; 3.9051x over previous
//
#include <hip/hip_runtime.h>
#include <hip/hip_bf16.h>

#define Bdim 32
#define Ndim 4096
#define Cdim 768
#define Kdim 64

typedef float f32x4 __attribute__((ext_vector_type(4)));
typedef short s16x8 __attribute__((ext_vector_type(8)));
typedef __bf16 bf16x8 __attribute__((ext_vector_type(8)));

__device__ __forceinline__ short f2bf(float f) {
  return __builtin_bit_cast(short, (__bf16)f);   // hw RNE cvt
}
__device__ __forceinline__ float bf2f(short s) {
  return (float)__builtin_bit_cast(__bf16, s);
}
__device__ __forceinline__ f32x4 MFMA(s16x8 a, s16x8 b, f32x4 c) {
  return __builtin_amdgcn_mfma_f32_16x16x32_bf16(
      __builtin_bit_cast(bf16x8, a), __builtin_bit_cast(bf16x8, b), c, 0, 0, 0);
}

// ---------------- k0: W fp32 -> bf16, fragment-order layout ----------------
// Wr unit u = ((cs*4 + t)*4 + g)*16 + i  (16B units of 8 bf16), so a wave's
// 64 lanes (g,i) read 1KB CONTIGUOUS per (cs,t) W-fragment load in k1.
__global__ void k0_wcvt(const float* __restrict__ W, short* __restrict__ Wr) {
  int idx = blockIdx.x * 256 + threadIdx.x;  // chunk of 8 elems; K*C/8 = 6144
  if (idx >= Kdim * Cdim / 8) return;
  int k = idx / (Cdim / 8), c8 = idx % (Cdim / 8);
  int cs = c8 >> 2, g = c8 & 3;
  int t = k >> 4, i = k & 15;
  const float* src = W + (size_t)k * Cdim + c8 * 8;
  s16x8 v;
#pragma unroll
  for (int e = 0; e < 8; ++e) v[e] = f2bf(src[e]);
  *(s16x8*)(Wr + ((((size_t)cs * 4 + t) * 4 + g) * 16 + i) * 8) = v;
}

// ---------------- k1: logits = x @ W^T (exotic layout) + fused per-tile stats ----
// K-loop unrolled x4: 24 loads (384B/thread) in flight per group -> MLP deep
// enough to saturate HBM (R7 diagnosis: 6 loads in flight = 20% HBM, all pipes idle).
__global__ __launch_bounds__(256) void k1_logits(
    const float* __restrict__ x, const short* __restrict__ Wr,
    short* __restrict__ Lx, float* __restrict__ pm, float* __restrict__ ps) {
  const int blk = blockIdx.x;
  const int b = blk >> 6;          // 64 ntiles per batch
  const int ntile = blk & 63;      // 64 rows per tile
  const int tid = threadIdx.x;
  const int w = tid >> 6;          // wave id 0..3 -> rows 16w..16w+15
  const int l = tid & 63;
  const int g = l >> 4, i = l & 15;

  const float* xrow = x + (size_t)(b * Ndim + ntile * 64 + w * 16 + i) * Cdim;
  f32x4 acc[4] = {};

  for (int grp = 0; grp < 6; ++grp) {   // 6 groups x (4 cs-steps of K=32)
    const int cbase = grp * 128 + g * 8;
    f32x4 xv[8];
    s16x8 wv[4][4];
#pragma unroll
    for (int s = 0; s < 4; ++s) {
      const f32x4* ap = (const f32x4*)(xrow + cbase + s * 32);
      xv[2 * s] = ap[0];
      xv[2 * s + 1] = ap[1];
    }
#pragma unroll
    for (int s = 0; s < 4; ++s) {
#pragma unroll
      for (int t = 0; t < 4; ++t) {
        // unit ((cs*4+t)*4+g)*16 + i, cs = grp*4+s  -> 1KB contiguous per wave
        wv[s][t] = *(const s16x8*)(
            Wr + ((((size_t)(grp * 4 + s) * 4 + t) * 4 + g) * 16 + i) * 8);
      }
    }
#pragma unroll
    for (int s = 0; s < 4; ++s) {
      s16x8 af;
#pragma unroll
      for (int e = 0; e < 4; ++e) af[e] = f2bf(xv[2 * s][e]);
#pragma unroll
      for (int e = 0; e < 4; ++e) af[4 + e] = f2bf(xv[2 * s + 1][e]);
#pragma unroll
      for (int t = 0; t < 4; ++t) acc[t] = MFMA(af, wv[s][t], acc[t]);
    }
  }

  // store logits (rounded) + keep rounded values for stats
  short* Lb = Lx + (size_t)b * (Ndim * Kdim);
  float rnd[4][4];
#pragma unroll
  for (int t = 0; t < 4; ++t) {
#pragma unroll
    for (int r = 0; r < 4; ++r) {
      int n = ntile * 64 + w * 16 + g * 4 + r;  // D row = 4*(l>>4)+reg
      int k = t * 16 + i;                       // D col = l&15
      short hv = f2bf(acc[t][r]);
      Lb[(n >> 3) * 512 + k * 8 + (n & 7)] = hv;
      rnd[t][r] = bf2f(hv);
    }
  }

  // ---- fused per-tile (max, sum-exp) over the tile's 64 n for each k ----
  __shared__ float rm[4][4][16], rs[4][4][16];  // [w][t][i]
  float tm[4];
#pragma unroll
  for (int t = 0; t < 4; ++t) {
    tm[t] = fmaxf(fmaxf(rnd[t][0], rnd[t][1]), fmaxf(rnd[t][2], rnd[t][3]));
    tm[t] = fmaxf(tm[t], __shfl_xor(tm[t], 16));
    tm[t] = fmaxf(tm[t], __shfl_xor(tm[t], 32));
  }
  if (g == 0) {
#pragma unroll
    for (int t = 0; t < 4; ++t) rm[w][t][i] = tm[t];
  }
  __syncthreads();
  float M[4], sv[4];
#pragma unroll
  for (int t = 0; t < 4; ++t) {
    M[t] = fmaxf(fmaxf(rm[0][t][i], rm[1][t][i]), fmaxf(rm[2][t][i], rm[3][t][i]));
    sv[t] = __expf(rnd[t][0] - M[t]) + __expf(rnd[t][1] - M[t]) +
            __expf(rnd[t][2] - M[t]) + __expf(rnd[t][3] - M[t]);
    sv[t] += __shfl_xor(sv[t], 16);
    sv[t] += __shfl_xor(sv[t], 32);
  }
  if (g == 0) {
#pragma unroll
    for (int t = 0; t < 4; ++t) rs[w][t][i] = sv[t];
  }
  __syncthreads();
  if (w == 0 && g == 0) {
#pragma unroll
    for (int t = 0; t < 4; ++t) {
      float S = rs[0][t][i] + rs[1][t][i] + rs[2][t][i] + rs[3][t][i];
      pm[((size_t)b * 64 + ntile) * 64 + t * 16 + i] = M[t];
      ps[((size_t)b * 64 + ntile) * 64 + t * 16 + i] = S;
    }
  }
}

// ---------------- k2b: combine 64 tile-partials -> m, 1/denom ----------------
__global__ __launch_bounds__(256) void k2b_combine(
    const float* __restrict__ pm, const float* __restrict__ ps,
    float* __restrict__ mout, float* __restrict__ invd) {
  const int idx = blockIdx.x * 256 + threadIdx.x;  // = b*64 + k
  const int b = idx >> 6, k = idx & 63;
  float am[64];
#pragma unroll 64
  for (int nt = 0; nt < 64; ++nt) am[nt] = pm[((size_t)b * 64 + nt) * 64 + k];
  float M = am[0];
#pragma unroll 64
  for (int nt = 1; nt < 64; ++nt) M = fmaxf(M, am[nt]);
  float S = 0.f;
#pragma unroll 64
  for (int nt = 0; nt < 64; ++nt)
    S += ps[((size_t)b * 64 + nt) * 64 + k] * __expf(am[nt] - M);
  mout[idx] = M;
  invd[idx] = 1.f / S;
}

// ---------------- k3: partial_q[b,k,c] = sum_{n in quarter q} exp(s-m) * x[b,n,c] ----
#define CT 48    // c-columns per block
#define NCH 128  // n rows staged per chunk
#define NQ 4     // n-splits
__device__ __forceinline__ int swz(int c) {
  return ((((c >> 3) ^ c) & 7) << 4);  // byte-XOR within a 256B row
}
__global__ __launch_bounds__(256) void k3_tokens(
    const float* __restrict__ x, const short* __restrict__ Lx,
    const float* __restrict__ mv, float* __restrict__ part) {
  __shared__ short xs[CT * 128];  // CT rows x 256 bytes
  char* xsb = (char*)xs;
  const int blk = blockIdx.x;
  const int q = blk & 3;
  const int ct = (blk >> 2) & 15;
  const int b = blk >> 6;
  const int tid = threadIdx.x;
  const int w = tid >> 6, l = tid & 63, g = l >> 4, i = l & 15;

  const float* xb = x + (size_t)b * Ndim * Cdim;
  const short* Lb = Lx + (size_t)b * (Ndim * Kdim);
  const float mk = mv[b * Kdim + w * 16 + i];  // A row k = w*16 + (l&15)

  f32x4 acc[3] = {};

#define LOADX(ch, buf)                                                        \
  do {                                                                        \
    const int n0_ = (ch) * NCH;                                               \
    _Pragma("unroll") for (int uu = 0; uu < 3; ++uu) {                        \
      int u_ = tid + uu * 256;                                                \
      int n_ = u_ / 6, c8_ = u_ % 6;                                          \
      const f32x4* src_ =                                                     \
          (const f32x4*)(xb + (size_t)(n0_ + n_) * Cdim + ct * CT + c8_ * 8); \
      buf[uu][0] = src_[0];                                                   \
      buf[uu][1] = src_[1];                                                   \
    }                                                                         \
  } while (0)

#define LOADL(ch, lvb)                                                        \
  do {                                                                        \
    const int nb8_ = (ch) * 16;                                               \
    _Pragma("unroll") for (int ns = 0; ns < 4; ++ns) {                        \
      lvb[ns] = *(const s16x8*)(Lb + (size_t)(nb8_ + ns * 4 + g) * 512 +      \
                                (w * 16 + i) * 8);                            \
    }                                                                         \
  } while (0)

#define STORELDS(buf)                                                         \
  do {                                                                        \
    _Pragma("unroll") for (int uu = 0; uu < 3; ++uu) {                        \
      int u_ = tid + uu * 256;                                                \
      int n_ = u_ / 6, c8_ = u_ % 6;                                          \
      _Pragma("unroll") for (int e = 0; e < 8; ++e) {                         \
        int c_ = c8_ * 8 + e;                                                 \
        float fv_ = (e < 4) ? buf[uu][0][e] : buf[uu][1][e - 4];              \
        *(short*)(xsb + c_ * 256 + ((2 * n_) ^ swz(c_))) = f2bf(fv_);         \
      }                                                                       \
    }                                                                         \
  } while (0)

#define COMPUTE(lvb)                                                          \
  do {                                                                        \
    _Pragma("unroll") for (int ns = 0; ns < 4; ++ns) {                        \
      s16x8 af_;                                                              \
      _Pragma("unroll") for (int e = 0; e < 8; ++e)                           \
          af_[e] = f2bf(__expf(bf2f(lvb[ns][e]) - mk));                       \
      _Pragma("unroll") for (int cs = 0; cs < 3; ++cs) {                      \
        const int c_ = cs * 16 + i;                                           \
        s16x8 bfr_ = *(const s16x8*)(xsb + c_ * 256 +                         \
                                     ((ns * 64 + g * 16) ^ swz(c_)));         \
        acc[cs] = MFMA(af_, bfr_, acc[cs]);                                   \
      }                                                                       \
    }                                                                         \
  } while (0)

  f32x4 stA[3][2], stB[3][2];
  s16x8 lvA[4], lvB[4];

  const int ch0 = q * 8;  // 8 chunks of 128 n per block
  LOADX(ch0, stA);
  LOADL(ch0, lvA);
  for (int ch = 0; ch < 8; ch += 2) {
    __syncthreads();          // prior chunk's LDS reads complete
    STORELDS(stA);
    LOADX(ch0 + ch + 1, stB);
    LOADL(ch0 + ch + 1, lvB);
    __syncthreads();          // LDS tile ready
    COMPUTE(lvA);
    __syncthreads();
    STORELDS(stB);
    if (ch + 2 < 8) {
      LOADX(ch0 + ch + 2, stA);
      LOADL(ch0 + ch + 2, lvA);
    }
    __syncthreads();
    COMPUTE(lvB);
  }

  float* pb = part + ((size_t)q * Bdim + b) * (Kdim * Cdim);
#pragma unroll
  for (int r = 0; r < 4; ++r) {
    const int k = w * 16 + g * 4 + r;  // D row
#pragma unroll
    for (int cs = 0; cs < 3; ++cs) {
      pb[(size_t)k * Cdim + ct * CT + cs * 16 + i] = acc[cs][r];  // D col = i
    }
  }
#undef LOADX
#undef LOADL
#undef STORELDS
#undef COMPUTE
}

// ---------------- k4: out = invd * sum_q part[q] ----------------
#define QSTRIDE (Bdim * Kdim * Cdim / 4)  // f32x4 units per q-slice = 393216
__global__ __launch_bounds__(256) void k4_reduce(
    const float* __restrict__ part, const float* __restrict__ invd,
    float* __restrict__ out) {
  const int idx = blockIdx.x * 256 + threadIdx.x;  // f32x4 unit index
  const f32x4* p = (const f32x4*)part;
  f32x4 s = p[idx] + p[idx + QSTRIDE] + p[idx + 2 * QSTRIDE] + p[idx + 3 * QSTRIDE];
  const float sc = invd[(idx * 4) / Cdim];  // (b*64+k)
  ((f32x4*)out)[idx] = s * sc;
}

extern "C" void kernel_launch(void* const* d_in, const int* in_sizes, int n_in,
                              void* d_out, int out_size, void* d_ws, size_t ws_size,
                              hipStream_t stream) {
  const float* x = (const float*)d_in[0];
  const float* W = (const float*)d_in[1];
  float* out = (float*)d_out;
  char* ws = (char*)d_ws;

  short* Wb = (short*)ws;                                   // 96 KB (pad 128K)
  short* Lx = (short*)(ws + (1 << 17));                     // 16 MB bf16 logits
  char* after = ws + (1 << 17) + (size_t)Bdim * Ndim * Kdim * 2;
  float* pm = (float*)after;                                // [32][64][64] tile max
  float* psum = pm + Bdim * 64 * 64;                        // [32][64][64] tile sum
  float* mv = psum + Bdim * 64 * 64;                        // 2048 max
  float* iv = mv + Bdim * Kdim;                             // 2048 inv-denom
  float* part = iv + Bdim * Kdim;                           // [4][32][64][768] fp32

  hipLaunchKernelGGL(k0_wcvt, dim3(24), dim3(256), 0, stream, W, Wb);
  hipLaunchKernelGGL(k1_logits, dim3(Bdim * 64), dim3(256), 0, stream, x, Wb, Lx, pm, psum);
  hipLaunchKernelGGL(k2b_combine, dim3(8), dim3(256), 0, stream, pm, psum, mv, iv);
  hipLaunchKernelGGL(k3_tokens, dim3(Bdim * 16 * NQ), dim3(256), 0, stream, x, Lx, mv, part);
  hipLaunchKernelGGL(k4_reduce, dim3(Bdim * Kdim * Cdim / 4 / 256), dim3(256), 0, stream,
                     part, iv, out);
}